// Round 1
// 222.515 us; speedup vs baseline: 1.0287x; 1.0287x over previous
//
#include <hip/hip_runtime.h>

// GroupSort: x[32,256,64,64] fp32. For each channel pair (2k, 2k+1):
//   d = x[2k] - x[2k+1]; r = relu(d); out[2k] = x[2k] - r; out[2k+1] = x[2k+1] + r
// Pure streaming elementwise op: 128 MiB in + 128 MiB out, zero reuse.
// -> nontemporal loads/stores (nt) to avoid cache write-allocate churn.
//
// COALESCING FIX (R1): previous version had each thread own two CONSECUTIVE
// float4 slots -> within one dwordx4 instruction, lanes sat at stride 32 B
// (half of every 64 B line per transaction). With nt stores bypassing L2's
// write-combining, those partial-line writes force RMW at the memory
// controller (~3.9 TB/s observed vs 6.6 TB/s for the fill kernel).
// Now each thread owns slot `within` and slot `within + 512` of the
// 1024-float4 plane: every load/store instruction is a perfectly contiguous
// 64 lanes x 16 B = 1024 B wave transaction.
//
// Layout: plane = H*W = 4096 floats = 1024 float4. Pair stride = 2 planes.
// 512 threads per plane-pair; 4096 plane-pairs; 2,097,152 threads total.

typedef float f32x4 __attribute__((ext_vector_type(4)));

__device__ __forceinline__ f32x4 nt_load4(const f32x4* p) {
    return __builtin_nontemporal_load(p);
}
__device__ __forceinline__ void nt_store4(f32x4* p, f32x4 v) {
    __builtin_nontemporal_store(v, p);
}

__device__ __forceinline__ void pair_op(const f32x4 a, const f32x4 b,
                                        f32x4& lo, f32x4& hi) {
#pragma unroll
    for (int i = 0; i < 4; ++i) {
        float d = a[i] - b[i];
        float r = d > 0.0f ? d : 0.0f;
        lo[i] = a[i] - r;
        hi[i] = b[i] + r;
    }
}

__global__ __launch_bounds__(256) void groupsort_kernel(
    const f32x4* __restrict__ x, f32x4* __restrict__ out) {
    const long t = (long)blockIdx.x * blockDim.x + threadIdx.x;
    const long pair   = t >> 9;          // 512 threads per plane-pair
    const long within = t & 511;         // contiguous across the wave
    const long base = pair * 2048 + within;

    // even plane: [base, base+512); odd plane: +1024 float4 (+16 KiB)
    const f32x4 a0 = nt_load4(x + base);
    const f32x4 a1 = nt_load4(x + base + 512);
    const f32x4 b0 = nt_load4(x + base + 1024);
    const f32x4 b1 = nt_load4(x + base + 1536);

    f32x4 lo0, hi0, lo1, hi1;
    pair_op(a0, b0, lo0, hi0);
    pair_op(a1, b1, lo1, hi1);

    nt_store4(out + base,        lo0);
    nt_store4(out + base + 512,  lo1);
    nt_store4(out + base + 1024, hi0);
    nt_store4(out + base + 1536, hi1);
}

extern "C" void kernel_launch(void* const* d_in, const int* in_sizes, int n_in,
                              void* d_out, int out_size, void* d_ws, size_t ws_size,
                              hipStream_t stream) {
    const f32x4* x = (const f32x4*)d_in[0];
    f32x4* out = (f32x4*)d_out;
    // total float4 per side: 4,194,304; 2 per thread -> 2,097,152 threads
    const int threads = 256;
    const int blocks = 2097152 / threads; // 8192
    groupsort_kernel<<<blocks, threads, 0, stream>>>(x, out);
}